// Round 5
// baseline (443.752 us; speedup 1.0000x reference)
//
#include <hip/hip_runtime.h>
#include <stdint.h>

// Problem constants
#define Bsz 1024
#define Tn  20
#define Hn  768
#define G4n 3072   // 4*H

// Workspace layout (floats):
//  [0..31]      Sh[t]     : only Sh[0] used (from GEMM atomics)
//  [32..63]     Sev[t]    : sum of batch_event[:,t,:]
//  [64..1087]   part[2][256] uint64 {token<<32|float}: 2-PHASE token barrier
//               (2 phases required: fast block may publish token t before a
//                slow block consumed token t-1 from the same slot)
//  [1088..]     rowsum[20][3072]
//  [+61440]     biassum[20][3072]
//  [+61440]     c0 handoff [1024][768]
#define WS_SH    0
#define WS_SEV   32
#define WS_PART  64
#define WS_RS    1088
#define WS_BS    (1088 + Tn*G4n)
#define WS_C     (1088 + 2*Tn*G4n)

// kernel A block ranges: GEMM + biassum + Sev (share the big-LDS kernel)
#define NB_GEMM   768
#define NB_BIAS   240
#define NB_SEV    1216
#define NB_A      (NB_GEMM + NB_BIAS + NB_SEV)
// kernel B: rowsum only, zero LDS, high occupancy
#define NB_ROWSUM 3648   // 58368 rows / 16 rows-per-block

typedef float  floatx4 __attribute__((ext_vector_type(4)));
typedef short  bfrag8  __attribute__((ext_vector_type(8)));

__device__ __forceinline__ float wave_reduce(float v){
#pragma unroll
    for (int o = 32; o > 0; o >>= 1) v += __shfl_down(v, o, 64);
    return v;
}
__device__ __forceinline__ float sigf(float x){ return 1.0f/(1.0f+__expf(-x)); }
__device__ __forceinline__ float tanhfast(float x){ return 2.0f/(1.0f+__expf(-2.0f*x)) - 1.0f; }
// truncating bf16 split (Dekker-style): hi = trunc(f), lo = trunc(f - hi).
// residual error is 2nd-order; 3-term MFMA covers it with big margin.
__device__ __forceinline__ unsigned short f2bf_t(float f){
    return (unsigned short)(__float_as_uint(f) >> 16);
}
__device__ __forceinline__ float bf2f(unsigned short h){ return __uint_as_float(((uint32_t)h)<<16); }
__device__ __forceinline__ uint64_t pack_tv(unsigned t, float v){
    return ((uint64_t)t << 32) | (uint64_t)__float_as_uint(v);
}

// ---------------- K0: zero scalar slots + token slots ----------------
__global__ void k_init(float* __restrict__ ws){
    for (int i = threadIdx.x; i < 1088; i += 1024) ws[i] = 0.0f;
}

// ---------------- KA: t=0 GEMM + biassum + Sev ----------------
__global__ __launch_bounds__(256) void k_gemm_sev(
    const float* __restrict__ price, const float* __restrict__ ev,
    const float* __restrict__ wih,   const float* __restrict__ whh,
    const float* __restrict__ bih,   const float* __restrict__ bhh,
    float* __restrict__ ws)
{
    __shared__ __align__(16) char smraw[4*64*56*2 + 16];
    unsigned short* Ah = (unsigned short*)smraw;
    unsigned short* Al = Ah + 64*56;
    unsigned short* Bh = Al + 64*56;
    unsigned short* Bl = Bh + 64*56;
    float* redk = (float*)(smraw + 4*64*56*2);
    float* red  = (float*)smraw;

    int blk = blockIdx.x, tid = threadIdx.x;

    if (blk < NB_GEMM) {
        // ----- GEMM for t=0 (bf16x3 split precision) -----
        float* Sh   = ws + WS_SH;
        float* cbuf = ws + WS_C;
        int bt = blk / 48, kt = blk % 48;
        int b0 = bt*64, k0 = kt*16;
        int w = tid >> 6, lane = tid & 63;
        int q = lane >> 4, col = lane & 15;

        int srow = tid >> 2;
        int kkoff = (tid & 3) * 8;
        int g_s = srow >> 4, rr = srow & 15;
        const float* aRow = ev  + (size_t)(b0 + srow)*(Tn*Hn);
        const float* bRow = whh + (size_t)(g_s*Hn + k0 + rr)*Hn;

        floatx4 acc[4];
#pragma unroll
        for (int g = 0; g < 4; ++g) acc[g] = (floatx4){0.f,0.f,0.f,0.f};

        for (int kk0 = 0; kk0 < Hn; kk0 += 32) {
            {
                const float* p = aRow + kk0 + kkoff;
                float4 v0 = *(const float4*)p;
                float4 v1 = *(const float4*)(p+4);
                float f[8] = {v0.x,v0.y,v0.z,v0.w,v1.x,v1.y,v1.z,v1.w};
                bfrag8 hv, lv;
#pragma unroll
                for (int i = 0; i < 8; ++i) {
                    unsigned short hb = f2bf_t(f[i]);
                    hv[i] = (short)hb;
                    lv[i] = (short)f2bf_t(f[i] - bf2f(hb));
                }
                *(bfrag8*)&Ah[srow*56 + kkoff] = hv;
                *(bfrag8*)&Al[srow*56 + kkoff] = lv;
                const float* pb = bRow + kk0 + kkoff;
                float4 u0 = *(const float4*)pb;
                float4 u1 = *(const float4*)(pb+4);
                float fb[8] = {u0.x,u0.y,u0.z,u0.w,u1.x,u1.y,u1.z,u1.w};
#pragma unroll
                for (int i = 0; i < 8; ++i) {
                    unsigned short hb = f2bf_t(fb[i]);
                    hv[i] = (short)hb;
                    lv[i] = (short)f2bf_t(fb[i] - bf2f(hb));
                }
                *(bfrag8*)&Bh[srow*56 + kkoff] = hv;
                *(bfrag8*)&Bl[srow*56 + kkoff] = lv;
            }
            __syncthreads();

            bfrag8 ah = *(const bfrag8*)&Ah[(w*16 + col)*56 + q*8];
            bfrag8 al = *(const bfrag8*)&Al[(w*16 + col)*56 + q*8];
#pragma unroll
            for (int g = 0; g < 4; ++g) {
                bfrag8 bh = *(const bfrag8*)&Bh[(g*16 + col)*56 + q*8];
                bfrag8 bl = *(const bfrag8*)&Bl[(g*16 + col)*56 + q*8];
                acc[g] = __builtin_amdgcn_mfma_f32_16x16x32_bf16(ah, bh, acc[g], 0,0,0);
                acc[g] = __builtin_amdgcn_mfma_f32_16x16x32_bf16(ah, bl, acc[g], 0,0,0);
                acc[g] = __builtin_amdgcn_mfma_f32_16x16x32_bf16(al, bh, acc[g], 0,0,0);
            }
            __syncthreads();
        }

        float hsum = 0.f;
#pragma unroll
        for (int r = 0; r < 4; ++r) {
            int b = b0 + w*16 + q*4 + r;
            float4 xv = *(const float4*)(price + (size_t)b*(Tn*4));
            float gates[4];
#pragma unroll
            for (int g = 0; g < 4; ++g) {
                int j = g*Hn + k0 + col;
                float4 wv = *(const float4*)(wih + (size_t)j*4);
                gates[g] = acc[g][r] + xv.x*wv.x + xv.y*wv.y + xv.z*wv.z + xv.w*wv.w
                         + bih[j] + bhh[j];
            }
            float c0 = sigf(gates[0]) * tanhfast(gates[2]);
            float h0 = sigf(gates[3]) * tanhfast(c0);
            cbuf[(size_t)b*Hn + k0 + col] = c0;
            hsum += h0;
        }
        hsum = wave_reduce(hsum);
        if (lane == 0) redk[w] = hsum;
        __syncthreads();
        if (tid == 0) atomicAdd(&ws[WS_SH], redk[0]+redk[1]+redk[2]+redk[3]);
        return;
    }

    blk -= NB_GEMM;
    float* Sev     = ws + WS_SEV;
    float* biassum = ws + WS_BS;

    if (blk < NB_BIAS) {                     // biassum
        int idx = blk*256 + tid;
        if (idx < Tn*G4n) biassum[idx] = bih[idx] + bhh[idx];
    } else {                                 // Sev[t], t=1..19, 64 blocks per t
        int sb = blk - NB_BIAS;
        int t  = 1 + (sb >> 6);
        int b0 = (sb & 63) * 16;
        float s = 0.f;
        for (int bb = 0; bb < 16; ++bb) {
            const float* base = ev + (size_t)(b0+bb)*(Tn*Hn) + (size_t)t*Hn;
            s += base[tid] + base[tid+256] + base[tid+512];
        }
        s = wave_reduce(s);
        if ((tid & 63) == 0) red[tid>>6] = s;
        __syncthreads();
        if (tid == 0) atomicAdd(&Sev[t], red[0]+red[1]+red[2]+red[3]);
    }
}

// ---------------- KB: rowsum streaming (zero LDS, 4 rows/wave ILP) ----------------
// 3648 blocks x 256 threads; wave handles 4 rows, 12 float4 loads in flight.
__global__ __launch_bounds__(256) void k_rowsum(
    const float* __restrict__ whh, float* __restrict__ ws)
{
    float* rowsum = ws + WS_RS;
    int tid = threadIdx.x, lane = tid & 63, wid = tid >> 6;
    int r0 = blockIdx.x*16 + wid*4;                 // 4 consecutive rows
    int t  = 1 + r0/G4n;                            // blocks never straddle t
    int j0 = r0 - (t-1)*G4n;
    const float* base = whh + (size_t)t*G4n*Hn + (size_t)j0*Hn;

    float s[4];
#pragma unroll
    for (int rr = 0; rr < 4; ++rr) {
        const float* p = base + (size_t)rr*Hn + lane*4;
        float4 a = *(const float4*)p;
        float4 b = *(const float4*)(p + 256);
        float4 c = *(const float4*)(p + 512);
        s[rr] = (a.x+a.y)+(a.z+a.w) + (b.x+b.y)+(b.z+b.w) + (c.x+c.y)+(c.z+c.w);
    }
#pragma unroll
    for (int rr = 0; rr < 4; ++rr) s[rr] = wave_reduce(s[rr]);
    if (lane == 0) {
#pragma unroll
        for (int rr = 0; rr < 4; ++rr) rowsum[t*G4n + j0 + rr] = s[rr];
    }
}

// ---------------- K2: persistent fused recurrence, t=1..19 ----------------
// 256 blocks x 768 threads. Decentralized 2-phase token barrier: every block
// publishes its partial (relaxed 8B store, payload inside the word) and polls
// all 256 slots itself — no block-0 aggregate hop, zero RMWs.
__global__ __launch_bounds__(768) void k_steps(
    const float* __restrict__ price, const float* __restrict__ wih,
    const float* __restrict__ fcw,   const float* __restrict__ fcb,
    float* __restrict__ ws, float* __restrict__ out)
{
    __shared__ float pr[4][80];      // price rows for this block's 4 b's
    __shared__ float red[12];        // hsum block reduce
    __shared__ float redP[4];        // token-poll reduce
    __shared__ float redF[4][12];

    float* Sh  = ws + WS_SH;
    float* Sev = ws + WS_SEV;
    uint64_t* part = (uint64_t*)(ws + WS_PART);     // [2][256]
    const float* rowsum  = ws + WS_RS;
    const float* biassum = ws + WS_BS;
    float* cbuf = ws + WS_C;

    int blk = blockIdx.x, tid = threadIdx.x;
    int lane = tid & 63, wid = tid >> 6;
    int k = tid;

    if (tid < 320) {
        int e = tid / 80, r = tid - e*80;
        pr[e][r] = price[(size_t)(blk + 256*e)*(Tn*4) + r];
    }

    float c[4];
#pragma unroll
    for (int e = 0; e < 4; ++e)
        c[e] = cbuf[(size_t)(blk + 256*e)*Hn + k];

    float fcwk = fcw[k];
    float fcb0 = fcb[0];
    __syncthreads();                 // pr[] ready

    float hsum_prev = 0.f;
    float vout[4] = {0.f,0.f,0.f,0.f};

    for (int t = 1; t < Tn; ++t) {
        // ---- preload step-t coefficients + hx-independent gate bases ----
        const float* wih_t = wih + (size_t)t*G4n*4;
        float rsv[4], base[4][4];
#pragma unroll
        for (int g = 0; g < 4; ++g) {
            int j = g*Hn + k;
            float4 wv = *(const float4*)(wih_t + (size_t)j*4);
            rsv[g]   = rowsum[t*G4n + j];
            float bs = biassum[t*G4n + j];
#pragma unroll
            for (int e = 0; e < 4; ++e) {
                base[e][g] = pr[e][t*4+0]*wv.x + pr[e][t*4+1]*wv.y
                           + pr[e][t*4+2]*wv.z + pr[e][t*4+3]*wv.w + bs;
            }
        }

        float hx;
        if (t == 1) {
            // kernel-boundary fence makes Sh[0]/Sev visible: no barrier needed
            hx = Sev[1] + Sh[0];
        } else {
            int ph = (t-1) & 1;
            // publish previous step's block partial (token t-1)
            float v = wave_reduce(hsum_prev);
            if (lane == 0) red[wid] = v;
            __syncthreads();
            if (tid == 0) {
                float tot = 0.f;
#pragma unroll
                for (int i = 0; i < 12; ++i) tot += red[i];
                __hip_atomic_store(&part[ph*256 + blk], pack_tv((unsigned)(t-1), tot),
                                   __ATOMIC_RELAXED, __HIP_MEMORY_SCOPE_AGENT);
            }
            // poll all 256 slots (lane-parallel), reduce locally
            if (tid < 256) {
                uint64_t u;
                do { u = __hip_atomic_load(&part[ph*256 + tid], __ATOMIC_RELAXED, __HIP_MEMORY_SCOPE_AGENT); }
                while ((unsigned)(u >> 32) != (unsigned)(t-1));
                float pv = wave_reduce(__uint_as_float((uint32_t)u));
                if (lane == 0) redP[wid] = pv;
            }
            __syncthreads();
            hx = Sev[t] + ((redP[0]+redP[1]) + (redP[2]+redP[3]));
        }

        // ---- cell update ----
        float hsum = 0.f;
#pragma unroll
        for (int e = 0; e < 4; ++e) {
            float gi = base[e][0] + hx*rsv[0];
            float gf = base[e][1] + hx*rsv[1];
            float gg = base[e][2] + hx*rsv[2];
            float go = base[e][3] + hx*rsv[3];
            float cn = sigf(gf)*c[e] + sigf(gi)*tanhfast(gg);
            c[e] = cn;
            float h = sigf(go)*tanhfast(cn);
            hsum += h;
            if (t == Tn-1) vout[e] = wave_reduce(h * fcwk);
        }
        hsum_prev = hsum;
    }

    // epilogue: out[b] = h19[b,:].fc_w + fc_b
    if (lane == 0) {
#pragma unroll
        for (int e = 0; e < 4; ++e) redF[e][wid] = vout[e];
    }
    __syncthreads();
    if (tid < 4) {
        float tot = 0.f;
#pragma unroll
        for (int i = 0; i < 12; ++i) tot += redF[tid][i];
        out[blk + 256*tid] = tot + fcb0;
    }
}

extern "C" void kernel_launch(void* const* d_in, const int* in_sizes, int n_in,
                              void* d_out, int out_size, void* d_ws, size_t ws_size,
                              hipStream_t stream)
{
    const float* price = (const float*)d_in[0];
    const float* ev    = (const float*)d_in[1];
    const float* wih   = (const float*)d_in[2];
    const float* whh   = (const float*)d_in[3];
    const float* bih   = (const float*)d_in[4];
    const float* bhh   = (const float*)d_in[5];
    const float* fcw   = (const float*)d_in[6];
    const float* fcb   = (const float*)d_in[7];
    float* out = (float*)d_out;
    float* ws  = (float*)d_ws;

    k_init    <<<1, 1024, 0, stream>>>(ws);
    k_rowsum  <<<NB_ROWSUM, 256, 0, stream>>>(whh, ws);
    k_gemm_sev<<<NB_A, 256, 0, stream>>>(price, ev, wih, whh, bih, bhh, ws);
    k_steps   <<<256, 768, 0, stream>>>(price, wih, fcw, fcb, ws, out);
}

// Round 6
// 441.553 us; speedup vs baseline: 1.0050x; 1.0050x over previous
//
#include <hip/hip_runtime.h>
#include <stdint.h>

// Problem constants
#define Bsz 1024
#define Tn  20
#define Hn  768
#define G4n 3072   // 4*H

// Workspace layout (floats):
//  [0..31]      Sh[t]     : only Sh[0] used (from GEMM atomics)
//  [32..63]     Sev[t]    : sum of batch_event[:,t,:]
//  [64..1119]   part[2][264] uint64 {token<<32|float}: 2-phase hierarchical
//               slots: [g*32+mi] member partials (mi=1..31), [256+g] group sums
//  [1120..1151] hxb[2][8] uint64 {token<<32|hx}: per-group hx broadcast
//  [1152..]     rowsum[20][3072]
//  [+61440]     biassum[20][3072]
//  [+61440]     c0 handoff [1024][768]
#define WS_SH    0
#define WS_SEV   32
#define WS_PART  64
#define WS_HXB   1120
#define WS_RS    1152
#define WS_BS    (1152 + Tn*G4n)
#define WS_C     (1152 + 2*Tn*G4n)

// kernel A block ranges: GEMM + biassum + Sev (share the big-LDS kernel)
#define NB_GEMM   768
#define NB_BIAS   240
#define NB_SEV    1216
#define NB_A      (NB_GEMM + NB_BIAS + NB_SEV)
// kernel B: rowsum only, zero LDS, high occupancy
#define NB_ROWSUM 3648   // 58368 rows / 16 rows-per-block

typedef float  floatx4 __attribute__((ext_vector_type(4)));
typedef short  bfrag8  __attribute__((ext_vector_type(8)));

__device__ __forceinline__ float wave_reduce(float v){
#pragma unroll
    for (int o = 32; o > 0; o >>= 1) v += __shfl_down(v, o, 64);
    return v;
}
__device__ __forceinline__ float sigf(float x){ return 1.0f/(1.0f+__expf(-x)); }
__device__ __forceinline__ float tanhfast(float x){ return 2.0f/(1.0f+__expf(-2.0f*x)) - 1.0f; }
// truncating bf16 split (Dekker-style): hi = trunc(f), lo = trunc(f - hi).
__device__ __forceinline__ unsigned short f2bf_t(float f){
    return (unsigned short)(__float_as_uint(f) >> 16);
}
__device__ __forceinline__ float bf2f(unsigned short h){ return __uint_as_float(((uint32_t)h)<<16); }
__device__ __forceinline__ uint64_t pack_tv(unsigned t, float v){
    return ((uint64_t)t << 32) | (uint64_t)__float_as_uint(v);
}

// ---------------- KA: t=0 GEMM + biassum + Sev ----------------
__global__ __launch_bounds__(256) void k_gemm_sev(
    const float* __restrict__ price, const float* __restrict__ ev,
    const float* __restrict__ wih,   const float* __restrict__ whh,
    const float* __restrict__ bih,   const float* __restrict__ bhh,
    float* __restrict__ ws)
{
    __shared__ __align__(16) char smraw[4*64*56*2 + 16];
    unsigned short* Ah = (unsigned short*)smraw;
    unsigned short* Al = Ah + 64*56;
    unsigned short* Bh = Al + 64*56;
    unsigned short* Bl = Bh + 64*56;
    float* redk = (float*)(smraw + 4*64*56*2);
    float* red  = (float*)smraw;

    int blk = blockIdx.x, tid = threadIdx.x;

    if (blk < NB_GEMM) {
        // ----- GEMM for t=0 (bf16x3 split precision) -----
        float* cbuf = ws + WS_C;
        int bt = blk / 48, kt = blk % 48;
        int b0 = bt*64, k0 = kt*16;
        int w = tid >> 6, lane = tid & 63;
        int q = lane >> 4, col = lane & 15;

        int srow = tid >> 2;
        int kkoff = (tid & 3) * 8;
        int g_s = srow >> 4, rr = srow & 15;
        const float* aRow = ev  + (size_t)(b0 + srow)*(Tn*Hn);
        const float* bRow = whh + (size_t)(g_s*Hn + k0 + rr)*Hn;

        floatx4 acc[4];
#pragma unroll
        for (int g = 0; g < 4; ++g) acc[g] = (floatx4){0.f,0.f,0.f,0.f};

        for (int kk0 = 0; kk0 < Hn; kk0 += 32) {
            {
                const float* p = aRow + kk0 + kkoff;
                float4 v0 = *(const float4*)p;
                float4 v1 = *(const float4*)(p+4);
                float f[8] = {v0.x,v0.y,v0.z,v0.w,v1.x,v1.y,v1.z,v1.w};
                bfrag8 hv, lv;
#pragma unroll
                for (int i = 0; i < 8; ++i) {
                    unsigned short hb = f2bf_t(f[i]);
                    hv[i] = (short)hb;
                    lv[i] = (short)f2bf_t(f[i] - bf2f(hb));
                }
                *(bfrag8*)&Ah[srow*56 + kkoff] = hv;
                *(bfrag8*)&Al[srow*56 + kkoff] = lv;
                const float* pb = bRow + kk0 + kkoff;
                float4 u0 = *(const float4*)pb;
                float4 u1 = *(const float4*)(pb+4);
                float fb[8] = {u0.x,u0.y,u0.z,u0.w,u1.x,u1.y,u1.z,u1.w};
#pragma unroll
                for (int i = 0; i < 8; ++i) {
                    unsigned short hb = f2bf_t(fb[i]);
                    hv[i] = (short)hb;
                    lv[i] = (short)f2bf_t(fb[i] - bf2f(hb));
                }
                *(bfrag8*)&Bh[srow*56 + kkoff] = hv;
                *(bfrag8*)&Bl[srow*56 + kkoff] = lv;
            }
            __syncthreads();

            bfrag8 ah = *(const bfrag8*)&Ah[(w*16 + col)*56 + q*8];
            bfrag8 al = *(const bfrag8*)&Al[(w*16 + col)*56 + q*8];
#pragma unroll
            for (int g = 0; g < 4; ++g) {
                bfrag8 bh = *(const bfrag8*)&Bh[(g*16 + col)*56 + q*8];
                bfrag8 bl = *(const bfrag8*)&Bl[(g*16 + col)*56 + q*8];
                acc[g] = __builtin_amdgcn_mfma_f32_16x16x32_bf16(ah, bh, acc[g], 0,0,0);
                acc[g] = __builtin_amdgcn_mfma_f32_16x16x32_bf16(ah, bl, acc[g], 0,0,0);
                acc[g] = __builtin_amdgcn_mfma_f32_16x16x32_bf16(al, bh, acc[g], 0,0,0);
            }
            __syncthreads();
        }

        float hsum = 0.f;
#pragma unroll
        for (int r = 0; r < 4; ++r) {
            int b = b0 + w*16 + q*4 + r;
            float4 xv = *(const float4*)(price + (size_t)b*(Tn*4));
            float gates[4];
#pragma unroll
            for (int g = 0; g < 4; ++g) {
                int j = g*Hn + k0 + col;
                float4 wv = *(const float4*)(wih + (size_t)j*4);
                gates[g] = acc[g][r] + xv.x*wv.x + xv.y*wv.y + xv.z*wv.z + xv.w*wv.w
                         + bih[j] + bhh[j];
            }
            float c0 = sigf(gates[0]) * tanhfast(gates[2]);
            float h0 = sigf(gates[3]) * tanhfast(c0);
            cbuf[(size_t)b*Hn + k0 + col] = c0;
            hsum += h0;
        }
        hsum = wave_reduce(hsum);
        if (lane == 0) redk[w] = hsum;
        __syncthreads();
        if (tid == 0) atomicAdd(&ws[WS_SH], redk[0]+redk[1]+redk[2]+redk[3]);
        return;
    }

    blk -= NB_GEMM;
    float* Sev     = ws + WS_SEV;
    float* biassum = ws + WS_BS;

    if (blk < NB_BIAS) {                     // biassum
        int idx = blk*256 + tid;
        if (idx < Tn*G4n) biassum[idx] = bih[idx] + bhh[idx];
    } else {                                 // Sev[t], t=1..19, 64 blocks per t
        int sb = blk - NB_BIAS;
        int t  = 1 + (sb >> 6);
        int b0 = (sb & 63) * 16;
        float s = 0.f;
        for (int bb = 0; bb < 16; ++bb) {
            const float* base = ev + (size_t)(b0+bb)*(Tn*Hn) + (size_t)t*Hn;
            s += base[tid] + base[tid+256] + base[tid+512];
        }
        s = wave_reduce(s);
        if ((tid & 63) == 0) red[tid>>6] = s;
        __syncthreads();
        if (tid == 0) atomicAdd(&Sev[t], red[0]+red[1]+red[2]+red[3]);
    }
}

// ---------------- KB: rowsum streaming (zero LDS) + scalar-slot init ----------------
__global__ __launch_bounds__(256) void k_rowsum(
    const float* __restrict__ whh, float* __restrict__ ws)
{
    float* rowsum = ws + WS_RS;
    int tid = threadIdx.x, lane = tid & 63, wid = tid >> 6;
    if (blockIdx.x == 0) {                         // fold k_init: zero scalar slots
        for (int i = tid; i < WS_RS; i += 256) ws[i] = 0.0f;
    }
    int r0 = blockIdx.x*16 + wid*4;                 // 4 consecutive rows
    int t  = 1 + r0/G4n;                            // blocks never straddle t
    int j0 = r0 - (t-1)*G4n;
    const float* base = whh + (size_t)t*G4n*Hn + (size_t)j0*Hn;

    float s[4];
#pragma unroll
    for (int rr = 0; rr < 4; ++rr) {
        const float* p = base + (size_t)rr*Hn + lane*4;
        float4 a = *(const float4*)p;
        float4 b = *(const float4*)(p + 256);
        float4 c = *(const float4*)(p + 512);
        s[rr] = (a.x+a.y)+(a.z+a.w) + (b.x+b.y)+(b.z+b.w) + (c.x+c.y)+(c.z+c.w);
    }
#pragma unroll
    for (int rr = 0; rr < 4; ++rr) s[rr] = wave_reduce(s[rr]);
    if (lane == 0) {
#pragma unroll
        for (int rr = 0; rr < 4; ++rr) rowsum[t*G4n + j0 + rr] = s[rr];
    }
}

// ---------------- K2: persistent fused recurrence, t=1..19 ----------------
// 256 blocks x 768 threads. Hierarchical 2-phase token barrier:
//  members (mi=1..31 of group g=blk>>5) publish 1 packed 8B partial;
//  leader (mi=0) polls its 31 slots, publishes group sum; leaders exchange
//  via one 64B line; each leader computes hx, publishes to hxb[g]; members
//  spin single-threaded on hxb[g]. ~30x less poll traffic than R5.
__global__ __launch_bounds__(768) void k_steps(
    const float* __restrict__ price, const float* __restrict__ wih,
    const float* __restrict__ fcw,   const float* __restrict__ fcb,
    float* __restrict__ ws, float* __restrict__ out)
{
    __shared__ float pr[4][80];      // price rows for this block's 4 b's
    __shared__ float red[12];        // hsum block reduce
    __shared__ float redF[4][12];
    __shared__ float shx;

    float* Sh  = ws + WS_SH;
    float* Sev = ws + WS_SEV;
    uint64_t* part = (uint64_t*)(ws + WS_PART);     // [2][264]
    uint64_t* hxb  = (uint64_t*)(ws + WS_HXB);      // [2][8]
    const float* rowsum  = ws + WS_RS;
    const float* biassum = ws + WS_BS;
    float* cbuf = ws + WS_C;

    int blk = blockIdx.x, tid = threadIdx.x;
    int lane = tid & 63, wid = tid >> 6;
    int k = tid;
    int g = blk >> 5, mi = blk & 31;
    bool isLeader = (mi == 0);

    if (tid < 320) {
        int e = tid / 80, r = tid - e*80;
        pr[e][r] = price[(size_t)(blk + 256*e)*(Tn*4) + r];
    }

    float c[4];
#pragma unroll
    for (int e = 0; e < 4; ++e)
        c[e] = cbuf[(size_t)(blk + 256*e)*Hn + k];

    float fcwk = fcw[k];
    float fcb0 = fcb[0];
    __syncthreads();                 // pr[] ready

    float hsum_prev = 0.f;

    for (int t = 1; t < Tn; ++t) {
        // ---- preload step-t coefficients + hx-independent gate bases ----
        const float* wih_t = wih + (size_t)t*G4n*4;
        float rsv[4], base[4][4];
#pragma unroll
        for (int gg = 0; gg < 4; ++gg) {
            int j = gg*Hn + k;
            float4 wv = *(const float4*)(wih_t + (size_t)j*4);
            rsv[gg]  = rowsum[t*G4n + j];
            float bs = biassum[t*G4n + j];
#pragma unroll
            for (int e = 0; e < 4; ++e) {
                base[e][gg] = pr[e][t*4+0]*wv.x + pr[e][t*4+1]*wv.y
                            + pr[e][t*4+2]*wv.z + pr[e][t*4+3]*wv.w + bs;
            }
        }

        float hx;
        if (t == 1) {
            // kernel-boundary fence makes Sh[0]/Sev visible: no barrier needed
            hx = Sev[1] + Sh[0];
        } else {
            int ph = (t-1) & 1;
            unsigned tok = (unsigned)(t-1);
            uint64_t* pp = part + (size_t)ph*264;

            // block partial of step t-1
            float v = wave_reduce(hsum_prev);
            if (lane == 0) red[wid] = v;
            __syncthreads();
            float tot = 0.f;
            if (tid == 0) {
#pragma unroll
                for (int i = 0; i < 12; ++i) tot += red[i];
                if (!isLeader)
                    __hip_atomic_store(&pp[g*32 + mi], pack_tv(tok, tot),
                                       __ATOMIC_RELAXED, __HIP_MEMORY_SCOPE_AGENT);
            }
            if (isLeader) {
                if (tid < 64) {      // wave 0 does the whole combine
                    float pv = 0.f;
                    if (tid >= 1 && tid < 32) {
                        uint64_t u;
                        do { u = __hip_atomic_load(&pp[g*32 + tid], __ATOMIC_RELAXED, __HIP_MEMORY_SCOPE_AGENT); }
                        while ((unsigned)(u >> 32) != tok);
                        pv = __uint_as_float((uint32_t)u);
                    } else if (tid == 0) pv = tot;
                    float gsum = wave_reduce(pv);
                    if (tid == 0)
                        __hip_atomic_store(&pp[256 + g], pack_tv(tok, gsum),
                                           __ATOMIC_RELAXED, __HIP_MEMORY_SCOPE_AGENT);
                    float gv = 0.f;
                    if (tid < 8) {
                        uint64_t u;
                        do { u = __hip_atomic_load(&pp[256 + tid], __ATOMIC_RELAXED, __HIP_MEMORY_SCOPE_AGENT); }
                        while ((unsigned)(u >> 32) != tok);
                        gv = __uint_as_float((uint32_t)u);
                    }
                    float tota = wave_reduce(gv);
                    if (tid == 0) {
                        float hxv = Sev[t] + tota;
                        shx = hxv;
                        __hip_atomic_store(&hxb[ph*8 + g], pack_tv((unsigned)t, hxv),
                                           __ATOMIC_RELAXED, __HIP_MEMORY_SCOPE_AGENT);
                    }
                }
            } else {
                if (tid == 0) {
                    uint64_t u;
                    do { u = __hip_atomic_load(&hxb[ph*8 + g], __ATOMIC_RELAXED, __HIP_MEMORY_SCOPE_AGENT); }
                    while ((unsigned)(u >> 32) != (unsigned)t);
                    shx = __uint_as_float((uint32_t)u);
                }
            }
            __syncthreads();
            hx = shx;
        }

        // ---- cell update ----
        float hsum = 0.f;
#pragma unroll
        for (int e = 0; e < 4; ++e) {
            float gi = base[e][0] + hx*rsv[0];
            float gf = base[e][1] + hx*rsv[1];
            float gg2 = base[e][2] + hx*rsv[2];
            float go = base[e][3] + hx*rsv[3];
            float cn = sigf(gf)*c[e] + sigf(gi)*tanhfast(gg2);
            c[e] = cn;
            float h = sigf(go)*tanhfast(cn);
            hsum += h;
            if (t == Tn-1) {
                float vo = wave_reduce(h * fcwk);
                if (lane == 0) redF[e][wid] = vo;
            }
        }
        hsum_prev = hsum;
    }

    // epilogue: out[b] = h19[b,:].fc_w + fc_b
    __syncthreads();
    if (tid < 4) {
        float tot = 0.f;
#pragma unroll
        for (int i = 0; i < 12; ++i) tot += redF[tid][i];
        out[blk + 256*tid] = tot + fcb0;
    }
}

extern "C" void kernel_launch(void* const* d_in, const int* in_sizes, int n_in,
                              void* d_out, int out_size, void* d_ws, size_t ws_size,
                              hipStream_t stream)
{
    const float* price = (const float*)d_in[0];
    const float* ev    = (const float*)d_in[1];
    const float* wih   = (const float*)d_in[2];
    const float* whh   = (const float*)d_in[3];
    const float* bih   = (const float*)d_in[4];
    const float* bhh   = (const float*)d_in[5];
    const float* fcw   = (const float*)d_in[6];
    const float* fcb   = (const float*)d_in[7];
    float* out = (float*)d_out;
    float* ws  = (float*)d_ws;

    k_rowsum  <<<NB_ROWSUM, 256, 0, stream>>>(whh, ws);
    k_gemm_sev<<<NB_A, 256, 0, stream>>>(price, ev, wih, whh, bih, bhh, ws);
    k_steps   <<<256, 768, 0, stream>>>(price, wih, fcw, fcb, ws, out);
}